// Round 1
// baseline (1018.212 us; speedup 1.0000x reference)
//
#include <hip/hip_runtime.h>
#include <hip/hip_bf16.h>

// Shapes (fixed per reference): B=65536, D_IN=256, D_HID=256, SHARE=2, NUM_GATE=6
#define BATCH   65536
#define KDIM    256
#define HDIM    256
#define BH      ((size_t)BATCH * HDIM)
#define TM      32          // batch rows per block

typedef __attribute__((ext_vector_type(8))) short  short8;   // 8 x bf16 (4 VGPRs)
typedef __attribute__((ext_vector_type(4))) float  f32x4;    // MFMA accumulator

__device__ __forceinline__ ushort f2bf(float f) {
    __hip_bfloat16 h = __float2bfloat16(f);
    return *reinterpret_cast<ushort*>(&h);
}

__device__ __forceinline__ float fsig(float x) {
    return 1.0f / (1.0f + __expf(-x));
}
__device__ __forceinline__ float ftanh(float x) {
    return 2.0f / (1.0f + __expf(-2.0f * x)) - 1.0f;
}

// ---- Prep: f32 weights -> pre-swizzled bf16 fragment stream ----------------
// Output layout: Wpk[tile][t][m][lane], 16B per entry, so the main kernel's
// per-(tile,t,m) weight load is base + lane*16B — one contiguous 1KB segment.
//   tile 0..15 : 16-unit column tile (unit = tile*16 + (lane&15))
//   t    0..7  : K-step (K=32 slice); chunk c = t*4 + (lane>>4)
//   m    0..11 : matrix row-set: 0..5 = ih gates, 6..9 = hh gates, 10..11 = sh
// Total entries: 16*8*12*64 = 98304 (1.5 MB).
__global__ __launch_bounds__(256) void prep_kernel(
    const float* __restrict__ wih, const float* __restrict__ whh,
    const float* __restrict__ wsh,
    const float* __restrict__ bih, const float* __restrict__ bhh,
    const float* __restrict__ bsh,
    ushort* __restrict__ wpk, float* __restrict__ cbias)
{
    const int gid = blockIdx.x * 256 + threadIdx.x;   // 0..98303

    const int lane = gid & 63;
    int rest = gid >> 6;
    const int m    = rest % 12;  rest /= 12;
    const int t    = rest & 7;
    const int tile = rest >> 3;

    const int col  = lane & 15;
    const int q    = lane >> 4;
    const int unit = tile * 16 + col;
    const int c    = t * 4 + q;              // 16B chunk (8 floats) within K=256

    const float* src; int row;
    if (m < 6)       { src = wih; row = m * 256 + unit; }
    else if (m < 10) { src = whh; row = (m - 6) * 256 + unit; }
    else             { src = wsh; row = (m - 10) * 256 + unit; }

    const float4* g = reinterpret_cast<const float4*>(src + row * 256 + c * 8);
    float4 a = g[0], b = g[1];
    union { short8 v; ushort u[8]; } pk;
    pk.u[0] = f2bf(a.x); pk.u[1] = f2bf(a.y);
    pk.u[2] = f2bf(a.z); pk.u[3] = f2bf(a.w);
    pk.u[4] = f2bf(b.x); pk.u[5] = f2bf(b.y);
    pk.u[6] = f2bf(b.z); pk.u[7] = f2bf(b.w);
    reinterpret_cast<short8*>(wpk)[gid] = pk.v;

    // combined biases: gates 0..3 -> bih+bhh, gates 4..5 -> bih+bsh
    if (gid < 1536) {
        float b2 = bih[gid] + (gid < 1024 ? bhh[gid] : bsh[gid - 1024]);
        cbias[gid] = b2;
    }
}

// ---- Fused cell kernel -----------------------------------------------------
// Block: 256 threads (4 waves). Rows [row0, row0+32). Wave w owns hidden
// units [w*64, w*64+64), processed as 4 col-tiles of 16 units.
// LDS: x/h/s tiles as bf16, 16B chunks XOR-swizzled: slot = chunk ^ (row&7).
// __launch_bounds__(256, 3): force <=170 unified regs -> 3 waves/SIMD
// (was 172 regs = 2 waves/SIMD, the occupancy cliff).
__global__ __launch_bounds__(256, 3) void lstm_kernel(
    const float* __restrict__ x, const float* __restrict__ h,
    const float* __restrict__ cmin, const float* __restrict__ smin,
    const float* __restrict__ mask, const int* __restrict__ idxp,
    const ushort* __restrict__ wpk, const float* __restrict__ cbias,
    float* __restrict__ out)
{
    __shared__ ushort lds[3][TM * KDIM];   // 3 x 16KB = 48KB -> 3 blocks/CU

    const int tid  = threadIdx.x;
    const int row0 = blockIdx.x * TM;
    const int idx  = idxp[0];
    const float* s = smin + (size_t)idx * BH;

    // ---- stage x, h, s[idx] rows into LDS as bf16 (swizzled 16B chunks) ----
    const float* srcs[3] = { x, h, s };
    #pragma unroll
    for (int si = 0; si < 3; ++si) {
        const float* src = srcs[si] + (size_t)row0 * KDIM;
        short8* dst = reinterpret_cast<short8*>(lds[si]);
        #pragma unroll
        for (int i = 0; i < 4; ++i) {
            int id = i * 256 + tid;          // 0..1023 chunk id
            int m  = id >> 5;                // row 0..31
            int c  = id & 31;                // 16B chunk within row
            int slot = c ^ (m & 7);
            const float4* g = reinterpret_cast<const float4*>(src + m * KDIM + c * 8);
            float4 a = g[0], b = g[1];
            union { short8 v; ushort u[8]; } pk;
            pk.u[0] = f2bf(a.x); pk.u[1] = f2bf(a.y);
            pk.u[2] = f2bf(a.z); pk.u[3] = f2bf(a.w);
            pk.u[4] = f2bf(b.x); pk.u[5] = f2bf(b.y);
            pk.u[6] = f2bf(b.z); pk.u[7] = f2bf(b.w);
            dst[m * 32 + slot] = pk.v;
        }
    }
    __syncthreads();

    const int lane = tid & 63;
    const int wave = tid >> 6;        // 0..3
    const int col  = lane & 15;       // MFMA n / m within tile
    const int q    = lane >> 4;       // quad -> k-slice / D-row group
    const int ub   = wave * 64;

    const short8* ldsx = reinterpret_cast<const short8*>(lds[0]);
    const short8* ldsh = reinterpret_cast<const short8*>(lds[1]);
    const short8* ldss = reinterpret_cast<const short8*>(lds[2]);
    const short8* Wp0  = reinterpret_cast<const short8*>(wpk);

    // mask depends only on row (same for every col-tile): prefetch once.
    float mkv[8];
    #pragma unroll
    for (int rt = 0; rt < 2; ++rt)
        #pragma unroll
        for (int r = 0; r < 4; ++r)
            mkv[rt * 4 + r] = mask[row0 + rt * 16 + q * 4 + r];

    for (int ct = 0; ct < 4; ++ct) {
        const int tileIdx = wave * 4 + ct;
        const int u0 = ub + ct * 16;
        const int j  = u0 + col;
        // fragment stream for this col-tile: [t][m][lane]
        const short8* Wp = Wp0 + (size_t)tileIdx * (8 * 12 * 64) + lane;

        // Prefetch epilogue operands now; ~900cy HBM latency hides under
        // the K-loop's MFMA + LDS work instead of stalling the epilogue.
        float cmv[8];
        #pragma unroll
        for (int rt = 0; rt < 2; ++rt)
            #pragma unroll
            for (int r = 0; r < 4; ++r)
                cmv[rt * 4 + r] =
                    cmin[(size_t)(row0 + rt * 16 + q * 4 + r) * HDIM + j];

        f32x4 accz[2][4];               // i, f, o, c_hat  (x2 row-tiles)
        f32x4 accb[2][2];               // b0, b1
        #pragma unroll
        for (int rt = 0; rt < 2; ++rt) {
            #pragma unroll
            for (int g = 0; g < 4; ++g) accz[rt][g] = (f32x4){0.f,0.f,0.f,0.f};
            #pragma unroll
            for (int g = 0; g < 2; ++g) accb[rt][g] = (f32x4){0.f,0.f,0.f,0.f};
        }

        #pragma unroll
        for (int t = 0; t < 8; ++t) {
            const int c = t * 4 + q;    // 16B chunk index within K=256
            // A fragments from LDS
            short8 ax[2], ah[2], as2[2];
            #pragma unroll
            for (int rt = 0; rt < 2; ++rt) {
                int m = rt * 16 + col;
                int o = m * 32 + (c ^ (m & 7));
                ax[rt] = ldsx[o]; ah[rt] = ldsh[o]; as2[rt] = ldss[o];
            }
            const short8* Wt = Wp + t * (12 * 64);

            // ---- phase 1: z-gates (ih 0..3 paired with hh 0..3) ----
            {
                short8 bz[8];
                #pragma unroll
                for (int g = 0; g < 4; ++g) {
                    bz[g]     = Wt[g * 64];          // ih gate g
                    bz[4 + g] = Wt[(6 + g) * 64];    // hh gate g
                }
                #pragma unroll
                for (int g = 0; g < 4; ++g) {
                    accz[0][g] = __builtin_amdgcn_mfma_f32_16x16x32_bf16(
                        ax[0], bz[g], accz[0][g], 0, 0, 0);
                    accz[1][g] = __builtin_amdgcn_mfma_f32_16x16x32_bf16(
                        ax[1], bz[g], accz[1][g], 0, 0, 0);
                    accz[0][g] = __builtin_amdgcn_mfma_f32_16x16x32_bf16(
                        ah[0], bz[4 + g], accz[0][g], 0, 0, 0);
                    accz[1][g] = __builtin_amdgcn_mfma_f32_16x16x32_bf16(
                        ah[1], bz[4 + g], accz[1][g], 0, 0, 0);
                }
            }
            // ---- phase 2: b-gates (ih 4..5 paired with sh 0..1) ----
            {
                short8 bb[4];
                #pragma unroll
                for (int g = 0; g < 2; ++g) {
                    bb[g]     = Wt[(4 + g) * 64];    // ih gate 4+g
                    bb[2 + g] = Wt[(10 + g) * 64];   // sh gate g
                }
                #pragma unroll
                for (int g = 0; g < 2; ++g) {
                    accb[0][g] = __builtin_amdgcn_mfma_f32_16x16x32_bf16(
                        ax[0], bb[g], accb[0][g], 0, 0, 0);
                    accb[1][g] = __builtin_amdgcn_mfma_f32_16x16x32_bf16(
                        ax[1], bb[g], accb[1][g], 0, 0, 0);
                    accb[0][g] = __builtin_amdgcn_mfma_f32_16x16x32_bf16(
                        as2[0], bb[2 + g], accb[0][g], 0, 0, 0);
                    accb[1][g] = __builtin_amdgcn_mfma_f32_16x16x32_bf16(
                        as2[1], bb[2 + g], accb[1][g], 0, 0, 0);
                }
            }
        }

        // ---- epilogue: activations + elementwise, direct stores ----
        float cb0 = cbias[0 * 256 + j], cb1 = cbias[1 * 256 + j];
        float cb2 = cbias[2 * 256 + j], cb3 = cbias[3 * 256 + j];
        float cb4 = cbias[4 * 256 + j], cb5 = cbias[5 * 256 + j];

        #pragma unroll
        for (int rt = 0; rt < 2; ++rt) {
            #pragma unroll
            for (int r = 0; r < 4; ++r) {
                const int row = row0 + rt * 16 + q * 4 + r;   // C/D: row = quad*4+reg
                const float mk = mkv[rt * 4 + r];
                const float cm = cmv[rt * 4 + r];
                float zi = accz[rt][0][r] + cb0;
                float zf = accz[rt][1][r] + cb1;
                float zo = accz[rt][2][r] + cb2;
                float zc = accz[rt][3][r] + cb3;
                float z0 = accb[rt][0][r] + cb4;
                float z1 = accb[rt][1][r] + cb5;

                float iv = fsig(zi), fv = fsig(zf), ov = fsig(zo);
                float ctv = (fv * cm + iv * ftanh(zc)) * mk;
                float tc  = ftanh(ctv) * mk;

                const size_t o = (size_t)row * HDIM + j;
                out[o]          = ov * tc;        // h
                out[BH + o]     = ctv;            // c_t
                out[2 * BH + o] = fsig(z0) * tc;  // s[0]
                out[3 * BH + o] = fsig(z1) * tc;  // s[1]
            }
        }
    }
}

extern "C" void kernel_launch(void* const* d_in, const int* in_sizes, int n_in,
                              void* d_out, int out_size, void* d_ws, size_t ws_size,
                              hipStream_t stream) {
    const float* input    = (const float*)d_in[0];
    const float* h_minors = (const float*)d_in[1];
    const float* c_minors = (const float*)d_in[2];
    const float* s_minors = (const float*)d_in[3];
    const float* mask     = (const float*)d_in[4];
    const float* wih      = (const float*)d_in[5];
    const float* whh      = (const float*)d_in[6];
    const float* wsh      = (const float*)d_in[7];
    const float* bih      = (const float*)d_in[8];
    const float* bhh      = (const float*)d_in[9];
    const float* bsh      = (const float*)d_in[10];
    const int*   idx      = (const int*)d_in[11];

    char* ws = (char*)d_ws;
    ushort* wpk  = (ushort*)(ws + 0);           // 98304*16B = 1572864
    float*  cbias = (float*)(ws + 1572864);     // 6*256*4   = 6144

    prep_kernel<<<384, 256, 0, stream>>>(wih, whh, wsh, bih, bhh, bsh,
                                         wpk, cbias);
    lstm_kernel<<<BATCH / TM, 256, 0, stream>>>(
        input, h_minors, c_minors, s_minors, mask, idx,
        wpk, cbias, (float*)d_out);
}

// Round 2
// 870.516 us; speedup vs baseline: 1.1697x; 1.1697x over previous
//
#include <hip/hip_runtime.h>
#include <hip/hip_bf16.h>

// Shapes (fixed per reference): B=65536, D_IN=256, D_HID=256, SHARE=2, NUM_GATE=6
#define BATCH   65536
#define KDIM    256
#define HDIM    256
#define BH      ((size_t)BATCH * HDIM)
#define TM      32          // batch rows per block

typedef __attribute__((ext_vector_type(8))) short  short8;   // 8 x bf16 (4 VGPRs)
typedef __attribute__((ext_vector_type(4))) float  f32x4;    // MFMA accumulator

__device__ __forceinline__ ushort f2bf(float f) {
    __hip_bfloat16 h = __float2bfloat16(f);
    return *reinterpret_cast<ushort*>(&h);
}

__device__ __forceinline__ float fsig(float x) {
    return 1.0f / (1.0f + __expf(-x));
}
__device__ __forceinline__ float ftanh(float x) {
    return 2.0f / (1.0f + __expf(-2.0f * x)) - 1.0f;
}

// ---- Prep: f32 weights -> pre-swizzled bf16 fragment stream ----------------
// Output layout: Wpk[tile][t][m][lane], 16B per entry, so the main kernel's
// per-(tile,t,m) weight load is base + lane*16B — one contiguous 1KB segment.
//   tile 0..15 : 16-unit column tile (unit = tile*16 + (lane&15))
//   t    0..7  : K-step (K=32 slice); chunk c = t*4 + (lane>>4)
//   m    0..11 : matrix row-set: 0..5 = ih gates, 6..9 = hh gates, 10..11 = sh
// Total entries: 16*8*12*64 = 98304 (1.5 MB).
__global__ __launch_bounds__(256) void prep_kernel(
    const float* __restrict__ wih, const float* __restrict__ whh,
    const float* __restrict__ wsh,
    const float* __restrict__ bih, const float* __restrict__ bhh,
    const float* __restrict__ bsh,
    ushort* __restrict__ wpk, float* __restrict__ cbias)
{
    const int gid = blockIdx.x * 256 + threadIdx.x;   // 0..98303

    const int lane = gid & 63;
    int rest = gid >> 6;
    const int m    = rest % 12;  rest /= 12;
    const int t    = rest & 7;
    const int tile = rest >> 3;

    const int col  = lane & 15;
    const int q    = lane >> 4;
    const int unit = tile * 16 + col;
    const int c    = t * 4 + q;              // 16B chunk (8 floats) within K=256

    const float* src; int row;
    if (m < 6)       { src = wih; row = m * 256 + unit; }
    else if (m < 10) { src = whh; row = (m - 6) * 256 + unit; }
    else             { src = wsh; row = (m - 10) * 256 + unit; }

    const float4* g = reinterpret_cast<const float4*>(src + row * 256 + c * 8);
    float4 a = g[0], b = g[1];
    union { short8 v; ushort u[8]; } pk;
    pk.u[0] = f2bf(a.x); pk.u[1] = f2bf(a.y);
    pk.u[2] = f2bf(a.z); pk.u[3] = f2bf(a.w);
    pk.u[4] = f2bf(b.x); pk.u[5] = f2bf(b.y);
    pk.u[6] = f2bf(b.z); pk.u[7] = f2bf(b.w);
    reinterpret_cast<short8*>(wpk)[gid] = pk.v;

    // combined biases: gates 0..3 -> bih+bhh, gates 4..5 -> bih+bsh
    if (gid < 1536) {
        float b2 = bih[gid] + (gid < 1024 ? bhh[gid] : bsh[gid - 1024]);
        cbias[gid] = b2;
    }
}

// ---- Fused cell kernel -----------------------------------------------------
// Block: 256 threads (4 waves). Rows [row0, row0+32). Wave w owns hidden
// units [w*64, w*64+64), processed as 2 PAIRS of 16-unit col-tiles.
// Pairing: K-loop(even tile) -> hold epilogue values in regs -> K-loop(odd
// tile) -> store both halves back-to-back. Each 128B output line (32 cols)
// is fully written within a few cycles -> no partial-line eviction / RMW
// (the round-1 regression: 3 blocks/CU made half-written lines spill L2,
// doubling HBM traffic).
// LDS: x/h/s tiles as bf16, 16B chunks XOR-swizzled: slot = chunk ^ (row&7).
__global__ __launch_bounds__(256, 3) void lstm_kernel(
    const float* __restrict__ x, const float* __restrict__ h,
    const float* __restrict__ cmin, const float* __restrict__ smin,
    const float* __restrict__ mask, const int* __restrict__ idxp,
    const ushort* __restrict__ wpk, const float* __restrict__ cbias,
    float* __restrict__ out)
{
    __shared__ ushort lds[3][TM * KDIM];   // 3 x 16KB = 48KB -> 3 blocks/CU

    const int tid  = threadIdx.x;
    const int row0 = blockIdx.x * TM;
    const int idx  = idxp[0];
    const float* s = smin + (size_t)idx * BH;

    // ---- stage x, h, s[idx] rows into LDS as bf16 (swizzled 16B chunks) ----
    const float* srcs[3] = { x, h, s };
    #pragma unroll
    for (int si = 0; si < 3; ++si) {
        const float* src = srcs[si] + (size_t)row0 * KDIM;
        short8* dst = reinterpret_cast<short8*>(lds[si]);
        #pragma unroll
        for (int i = 0; i < 4; ++i) {
            int id = i * 256 + tid;          // 0..1023 chunk id
            int m  = id >> 5;                // row 0..31
            int c  = id & 31;                // 16B chunk within row
            int slot = c ^ (m & 7);
            const float4* g = reinterpret_cast<const float4*>(src + m * KDIM + c * 8);
            float4 a = g[0], b = g[1];
            union { short8 v; ushort u[8]; } pk;
            pk.u[0] = f2bf(a.x); pk.u[1] = f2bf(a.y);
            pk.u[2] = f2bf(a.z); pk.u[3] = f2bf(a.w);
            pk.u[4] = f2bf(b.x); pk.u[5] = f2bf(b.y);
            pk.u[6] = f2bf(b.z); pk.u[7] = f2bf(b.w);
            dst[m * 32 + slot] = pk.v;
        }
    }
    __syncthreads();

    const int lane = tid & 63;
    const int wave = tid >> 6;        // 0..3
    const int col  = lane & 15;       // MFMA n / m within tile
    const int q    = lane >> 4;       // quad -> k-slice / D-row group
    const int ub   = wave * 64;

    const short8* ldsx = reinterpret_cast<const short8*>(lds[0]);
    const short8* ldsh = reinterpret_cast<const short8*>(lds[1]);
    const short8* ldss = reinterpret_cast<const short8*>(lds[2]);
    const short8* Wp0  = reinterpret_cast<const short8*>(wpk);

    // mask depends only on row (same for every col-tile): prefetch once.
    float mkv[2][4];
    #pragma unroll
    for (int rt = 0; rt < 2; ++rt)
        #pragma unroll
        for (int r = 0; r < 4; ++r)
            mkv[rt][r] = mask[row0 + rt * 16 + q * 4 + r];

    f32x4 accz[2][4];               // i, f, o, c_hat  (x2 row-tiles)
    f32x4 accb[2][2];               // b0, b1

    // K-loop over one 16-unit col-tile: accumulate 6 gate GEMMs.
    auto runK = [&](int tileIdx) {
        const short8* Wp = Wp0 + (size_t)tileIdx * (8 * 12 * 64) + lane;
        #pragma unroll
        for (int rt = 0; rt < 2; ++rt) {
            #pragma unroll
            for (int g = 0; g < 4; ++g) accz[rt][g] = (f32x4){0.f,0.f,0.f,0.f};
            #pragma unroll
            for (int g = 0; g < 2; ++g) accb[rt][g] = (f32x4){0.f,0.f,0.f,0.f};
        }
        #pragma unroll
        for (int t = 0; t < 8; ++t) {
            const int c = t * 4 + q;    // 16B chunk index within K=256
            short8 ax[2], ah[2], as2[2];
            #pragma unroll
            for (int rt = 0; rt < 2; ++rt) {
                int m = rt * 16 + col;
                int o = m * 32 + (c ^ (m & 7));
                ax[rt] = ldsx[o]; ah[rt] = ldsh[o]; as2[rt] = ldss[o];
            }
            const short8* Wt = Wp + t * (12 * 64);

            // phase 1: z-gates (ih 0..3 paired with hh 0..3)
            {
                short8 bz[8];
                #pragma unroll
                for (int g = 0; g < 4; ++g) {
                    bz[g]     = Wt[g * 64];          // ih gate g
                    bz[4 + g] = Wt[(6 + g) * 64];    // hh gate g
                }
                #pragma unroll
                for (int g = 0; g < 4; ++g) {
                    accz[0][g] = __builtin_amdgcn_mfma_f32_16x16x32_bf16(
                        ax[0], bz[g], accz[0][g], 0, 0, 0);
                    accz[1][g] = __builtin_amdgcn_mfma_f32_16x16x32_bf16(
                        ax[1], bz[g], accz[1][g], 0, 0, 0);
                    accz[0][g] = __builtin_amdgcn_mfma_f32_16x16x32_bf16(
                        ah[0], bz[4 + g], accz[0][g], 0, 0, 0);
                    accz[1][g] = __builtin_amdgcn_mfma_f32_16x16x32_bf16(
                        ah[1], bz[4 + g], accz[1][g], 0, 0, 0);
                }
            }
            // phase 2: b-gates (ih 4..5 paired with sh 0..1)
            {
                short8 bb[4];
                #pragma unroll
                for (int g = 0; g < 2; ++g) {
                    bb[g]     = Wt[(4 + g) * 64];    // ih gate 4+g
                    bb[2 + g] = Wt[(10 + g) * 64];   // sh gate g
                }
                #pragma unroll
                for (int g = 0; g < 2; ++g) {
                    accb[0][g] = __builtin_amdgcn_mfma_f32_16x16x32_bf16(
                        ax[0], bb[g], accb[0][g], 0, 0, 0);
                    accb[1][g] = __builtin_amdgcn_mfma_f32_16x16x32_bf16(
                        ax[1], bb[g], accb[1][g], 0, 0, 0);
                    accb[0][g] = __builtin_amdgcn_mfma_f32_16x16x32_bf16(
                        as2[0], bb[2 + g], accb[0][g], 0, 0, 0);
                    accb[1][g] = __builtin_amdgcn_mfma_f32_16x16x32_bf16(
                        as2[1], bb[2 + g], accb[1][g], 0, 0, 0);
                }
            }
        }
    };

    for (int cp = 0; cp < 2; ++cp) {
        const int u0 = ub + cp * 32;          // 128B-aligned column base

        // ---- half 0: K-loop + epilogue compute, stores DEFERRED ----
        runK(wave * 4 + cp * 2);
        float resA[2][4][4];                  // [rt][r][stream]
        {
            const int j = u0 + col;
            float cb0 = cbias[0 * 256 + j], cb1 = cbias[1 * 256 + j];
            float cb2 = cbias[2 * 256 + j], cb3 = cbias[3 * 256 + j];
            float cb4 = cbias[4 * 256 + j], cb5 = cbias[5 * 256 + j];
            float cmv[2][4];
            #pragma unroll
            for (int rt = 0; rt < 2; ++rt)
                #pragma unroll
                for (int r = 0; r < 4; ++r)
                    cmv[rt][r] =
                        cmin[(size_t)(row0 + rt * 16 + q * 4 + r) * HDIM + j];
            #pragma unroll
            for (int rt = 0; rt < 2; ++rt) {
                #pragma unroll
                for (int r = 0; r < 4; ++r) {
                    const float mk = mkv[rt][r];
                    const float cm = cmv[rt][r];
                    float zi = accz[rt][0][r] + cb0;
                    float zf = accz[rt][1][r] + cb1;
                    float zo = accz[rt][2][r] + cb2;
                    float zc = accz[rt][3][r] + cb3;
                    float z0 = accb[rt][0][r] + cb4;
                    float z1 = accb[rt][1][r] + cb5;
                    float iv = fsig(zi), fv = fsig(zf), ov = fsig(zo);
                    float ctv = (fv * cm + iv * ftanh(zc)) * mk;
                    float tc  = ftanh(ctv) * mk;
                    resA[rt][r][0] = ov * tc;
                    resA[rt][r][1] = ctv;
                    resA[rt][r][2] = fsig(z0) * tc;
                    resA[rt][r][3] = fsig(z1) * tc;
                }
            }
        }

        // ---- half 1: K-loop + epilogue, store BOTH halves (full lines) ----
        runK(wave * 4 + cp * 2 + 1);
        {
            const int j = u0 + 16 + col;
            float cb0 = cbias[0 * 256 + j], cb1 = cbias[1 * 256 + j];
            float cb2 = cbias[2 * 256 + j], cb3 = cbias[3 * 256 + j];
            float cb4 = cbias[4 * 256 + j], cb5 = cbias[5 * 256 + j];
            float cmv[2][4];
            #pragma unroll
            for (int rt = 0; rt < 2; ++rt)
                #pragma unroll
                for (int r = 0; r < 4; ++r)
                    cmv[rt][r] =
                        cmin[(size_t)(row0 + rt * 16 + q * 4 + r) * HDIM + j];
            #pragma unroll
            for (int rt = 0; rt < 2; ++rt) {
                #pragma unroll
                for (int r = 0; r < 4; ++r) {
                    const int row = row0 + rt * 16 + q * 4 + r;
                    const float mk = mkv[rt][r];
                    const float cm = cmv[rt][r];
                    float zi = accz[rt][0][r] + cb0;
                    float zf = accz[rt][1][r] + cb1;
                    float zo = accz[rt][2][r] + cb2;
                    float zc = accz[rt][3][r] + cb3;
                    float z0 = accb[rt][0][r] + cb4;
                    float z1 = accb[rt][1][r] + cb5;
                    float iv = fsig(zi), fv = fsig(zf), ov = fsig(zo);
                    float ctv = (fv * cm + iv * ftanh(zc)) * mk;
                    float tc  = ftanh(ctv) * mk;

                    const size_t oA = (size_t)row * HDIM + (j - 16);
                    const size_t oB = oA + 16;
                    out[oA]          = resA[rt][r][0];
                    out[oB]          = ov * tc;        // h
                    out[BH + oA]     = resA[rt][r][1];
                    out[BH + oB]     = ctv;            // c_t
                    out[2 * BH + oA] = resA[rt][r][2];
                    out[2 * BH + oB] = fsig(z0) * tc;  // s[0]
                    out[3 * BH + oA] = resA[rt][r][3];
                    out[3 * BH + oB] = fsig(z1) * tc;  // s[1]
                }
            }
        }
    }
}

extern "C" void kernel_launch(void* const* d_in, const int* in_sizes, int n_in,
                              void* d_out, int out_size, void* d_ws, size_t ws_size,
                              hipStream_t stream) {
    const float* input    = (const float*)d_in[0];
    const float* h_minors = (const float*)d_in[1];
    const float* c_minors = (const float*)d_in[2];
    const float* s_minors = (const float*)d_in[3];
    const float* mask     = (const float*)d_in[4];
    const float* wih      = (const float*)d_in[5];
    const float* whh      = (const float*)d_in[6];
    const float* wsh      = (const float*)d_in[7];
    const float* bih      = (const float*)d_in[8];
    const float* bhh      = (const float*)d_in[9];
    const float* bsh      = (const float*)d_in[10];
    const int*   idx      = (const int*)d_in[11];

    char* ws = (char*)d_ws;
    ushort* wpk  = (ushort*)(ws + 0);           // 98304*16B = 1572864
    float*  cbias = (float*)(ws + 1572864);     // 6*256*4   = 6144

    prep_kernel<<<384, 256, 0, stream>>>(wih, whh, wsh, bih, bhh, bsh,
                                         wpk, cbias);
    lstm_kernel<<<BATCH / TM, 256, 0, stream>>>(
        input, h_minors, c_minors, s_minors, mask, idx,
        wpk, cbias, (float*)d_out);
}